// Round 2
// baseline (130.493 us; speedup 1.0000x reference)
//
#include <hip/hip_runtime.h>
#include <hip/hip_bf16.h>

// AutoInt fused kernels for MI355X (gfx950).
//
// Reference: X (4096,128) f32 -> 3x InteractingLayer (1x1 scalar weights)
//            -> DNN 128->256->128->1.
//
// Key simplification: wq/wk/wv/wr are SCALARS, so per layer l and row b:
//   out[f] = relu( wv * (sum_g e_fg * x_g)/(sum_g e_fg) + wr * x_f )
//   with e_fg = exp(c * x_f * x_g),  c = wq*wk.
// Softmax max-subtraction is algebraically a no-op for the num/den ratio and
// logits are tiny (|c*x_f*x_g| < ~0.5), so we exponentiate directly with the
// native v_exp_f32 (2^x), folding log2(e) into c.

#define FDIM 128
#define NLAYER 3
#define H1 256
#define H2 128
#define RPB 8          // rows per block in the DNN kernel

// ---------------- Kernel A: 3 fused interacting layers ----------------
// One block per batch row; 128 threads = one thread per field.
// Expected: trans-pipe bound (~201M v_exp_f32 total), ~10-18 us.
__global__ __launch_bounds__(FDIM) void autoint_attn_kernel(
    const float* __restrict__ X,
    const float* __restrict__ wq, const float* __restrict__ wk,
    const float* __restrict__ wv, const float* __restrict__ wr,
    float* __restrict__ att)
{
    __shared__ float sx[FDIM];
    const int b = blockIdx.x;
    const int f = threadIdx.x;

    float xf = X[b * FDIM + f];
    sx[f] = xf;
    __syncthreads();

    #pragma unroll
    for (int l = 0; l < NLAYER; ++l) {
        const float c  = wq[l] * wk[l] * 1.4426950408889634f; // fold log2(e)
        const float vv = wv[l];
        const float rr = wr[l];

        const float a = c * xf;          // per-thread row coefficient
        float den = 0.f, num = 0.f;

        #pragma unroll 2
        for (int g = 0; g < FDIM; g += 4) {
            // all lanes read the same 16B -> LDS broadcast, conflict-free
            float4 xg = *reinterpret_cast<const float4*>(&sx[g]);
            float e0 = __builtin_amdgcn_exp2f(a * xg.x);
            float e1 = __builtin_amdgcn_exp2f(a * xg.y);
            float e2 = __builtin_amdgcn_exp2f(a * xg.z);
            float e3 = __builtin_amdgcn_exp2f(a * xg.w);
            den += (e0 + e1) + (e2 + e3);
            num = fmaf(e0, xg.x, num);
            num = fmaf(e1, xg.y, num);
            num = fmaf(e2, xg.z, num);
            num = fmaf(e3, xg.w, num);
        }

        float o = fmaf(rr, xf, vv * num / den);
        o = fmaxf(o, 0.f);

        __syncthreads();      // everyone done reading sx for this layer
        sx[f] = o;
        xf = o;
        __syncthreads();
    }

    att[b * FDIM + f] = xf;
}

// ---------------- Kernel B: fused DNN 128 -> 256 -> 128 -> 1 ----------------
// 8 rows per block (256 threads): every W1/W2 element loaded from L2 feeds
// 8 FMAs. LDS: 8x128 input + 8x256 hidden = 12 KB. 512 blocks = 2/CU.
__global__ __launch_bounds__(256) void autoint_dnn_kernel(
    const float* __restrict__ att,
    const float* __restrict__ W1, const float* __restrict__ b1,
    const float* __restrict__ W2, const float* __restrict__ b2,
    const float* __restrict__ Wf,
    float* __restrict__ out)
{
    __shared__ float sh[RPB][FDIM];    // input rows
    __shared__ float sh1[RPB][H1];     // hidden-1 rows
    __shared__ float red[RPB][2];      // cross-wave reduction

    const int tid = threadIdx.x;
    const int b0  = blockIdx.x * RPB;

    // cooperative load of 8 rows (1024 floats, coalesced)
    #pragma unroll
    for (int i = tid; i < RPB * FDIM; i += 256)
        sh[i >> 7][i & (FDIM - 1)] = att[b0 * FDIM + i];
    __syncthreads();

    // ---- stage 1: h1[j] = relu(b1[j] + sum_i h[i] * W1[i][j]), j = tid ----
    {
        float acc[RPB];
        const float bb = b1[tid];
        #pragma unroll
        for (int r = 0; r < RPB; ++r) acc[r] = bb;

        #pragma unroll 4
        for (int i = 0; i < FDIM; ++i) {
            const float w = W1[i * H1 + tid];        // coalesced, L2-hot
            #pragma unroll
            for (int r = 0; r < RPB; ++r)
                acc[r] = fmaf(sh[r][i], w, acc[r]);  // sh[r][i]: LDS broadcast
        }
        #pragma unroll
        for (int r = 0; r < RPB; ++r)
            sh1[r][tid] = fmaxf(acc[r], 0.f);
    }
    __syncthreads();

    // ---- stage 2: h2[k] + final dot with Wf. 256 threads = 2 groups of 128;
    //      group g (tid>>7) handles rows 4g..4g+3; thread covers k = tid&127. ----
    {
        const int k  = tid & (H2 - 1);
        const int rb = (tid >> 7) * 4;           // 0 or 4
        float acc[4];
        const float bb = b2[k];
        #pragma unroll
        for (int r = 0; r < 4; ++r) acc[r] = bb;

        #pragma unroll 4
        for (int j = 0; j < H1; ++j) {
            const float w = W2[j * H2 + k];      // coalesced, L2-hot
            #pragma unroll
            for (int r = 0; r < 4; ++r)
                acc[r] = fmaf(sh1[rb + r][j], w, acc[r]);
        }

        const float wf = Wf[k];
        float p[4];
        #pragma unroll
        for (int r = 0; r < 4; ++r)
            p[r] = fmaxf(acc[r], 0.f) * wf;

        // reduce 128 k-partials per row: butterfly within each 64-lane wave,
        // then combine the group's 2 waves through LDS.
        #pragma unroll
        for (int off = 32; off >= 1; off >>= 1) {
            #pragma unroll
            for (int r = 0; r < 4; ++r)
                p[r] += __shfl_down(p[r], off, 64);
        }
        const int lane = tid & 63;
        const int wave = tid >> 6;               // 0..3
        if (lane == 0) {
            #pragma unroll
            for (int r = 0; r < 4; ++r)
                red[rb + r][wave & 1] = p[r];    // waves {0,2} -> col 0, {1,3} -> col 1
        }
    }
    __syncthreads();

    if (tid < RPB)
        out[b0 + tid] = red[tid][0] + red[tid][1];
}

extern "C" void kernel_launch(void* const* d_in, const int* in_sizes, int n_in,
                              void* d_out, int out_size, void* d_ws, size_t ws_size,
                              hipStream_t stream) {
    const float* X  = (const float*)d_in[0];
    const float* wq = (const float*)d_in[1];
    const float* wk = (const float*)d_in[2];
    const float* wv = (const float*)d_in[3];
    const float* wr = (const float*)d_in[4];
    const float* W1 = (const float*)d_in[5];
    const float* b1 = (const float*)d_in[6];
    const float* W2 = (const float*)d_in[7];
    const float* b2 = (const float*)d_in[8];
    const float* Wf = (const float*)d_in[9];
    float* out = (float*)d_out;

    const int B = in_sizes[0] / FDIM;       // 4096
    float* att = (float*)d_ws;              // B*FDIM floats = 2 MB scratch

    autoint_attn_kernel<<<dim3(B), dim3(FDIM), 0, stream>>>(
        X, wq, wk, wv, wr, att);
    autoint_dnn_kernel<<<dim3(B / RPB), dim3(256), 0, stream>>>(
        att, W1, b1, W2, b2, Wf, out);
}

// Round 10
// 128.409 us; speedup vs baseline: 1.0162x; 1.0162x over previous
//
#include <hip/hip_runtime.h>
#include <hip/hip_bf16.h>

// AutoInt fully-fused kernel for MI355X (gfx950).
//
// Reference: X (4096,128) f32 -> 3x InteractingLayer (1x1 SCALAR weights)
//            -> DNN 128->256->128->1.
//
// Per layer l, row b:  out[f] = relu( wv*(sum_g e_fg*x_g)/(sum_g e_fg) + wr*x_f ),
// e_fg = exp(c*x_f*x_g), c = wq*wk (scalars). log2(e) folded into c, native
// v_exp_f32. Softmax max-subtraction cancels in the num/den ratio and logits
// are tiny, so direct exponentiation is exact-enough (validated absmax 2e-13
// in R2's two-kernel version).
//
// Design: ONE kernel, 512 blocks x 1024 threads (8 rows/block).
//  - attn phase: thread=(row,field); same math as the R1/R2 passing kernel.
//  - DNN phase: K-split GEMV-style with LDS partial reduction; 32 waves/CU
//    (vs 8 in the R2 dnn kernel, which was latency-bound: 19% VALUBusy,
//    19.7% occupancy, 44 us).

#define FDIM 128
#define NLAYER 3
#define RPB 8           // batch rows per block
#define H1 256
#define H2 128

__global__ __launch_bounds__(1024) void autoint_fused(
    const float* __restrict__ X,
    const float* __restrict__ wq, const float* __restrict__ wk,
    const float* __restrict__ wv, const float* __restrict__ wr,
    const float* __restrict__ W1, const float* __restrict__ b1,
    const float* __restrict__ W2, const float* __restrict__ b2,
    const float* __restrict__ Wf,
    float* __restrict__ out)
{
    __shared__ float sx[RPB][FDIM];    // 4 KB: input/att rows
    __shared__ float sh1[RPB][H1];     // 8 KB: hidden-1 rows
    __shared__ float part[8192];       // 32 KB: K-split partials (both stages)
    __shared__ float red[RPB][2];      // cross-wave final reduction

    const int tid = threadIdx.x;
    const int b0  = blockIdx.x * RPB;

    // ---------------- load 8 rows (coalesced: 1 float/thread) --------------
    const int r = tid >> 7;            // 0..7  (row within block)
    const int f = tid & 127;           // 0..127 (field)
    float xf = X[(b0 + r) * FDIM + f];
    sx[r][f] = xf;
    __syncthreads();

    // ---------------- 3 fused interacting layers ---------------------------
    #pragma unroll
    for (int l = 0; l < NLAYER; ++l) {
        const float c  = wq[l] * wk[l] * 1.4426950408889634f; // fold log2(e)
        const float vv = wv[l];
        const float rr = wr[l];

        const float a = c * xf;
        float den = 0.f, num = 0.f;

        #pragma unroll 4
        for (int g = 0; g < FDIM; g += 4) {
            // whole wave reads the same 16B of its row -> LDS broadcast
            float4 xg = *reinterpret_cast<const float4*>(&sx[r][g]);
            float e0 = __builtin_amdgcn_exp2f(a * xg.x);
            float e1 = __builtin_amdgcn_exp2f(a * xg.y);
            float e2 = __builtin_amdgcn_exp2f(a * xg.z);
            float e3 = __builtin_amdgcn_exp2f(a * xg.w);
            den += (e0 + e1) + (e2 + e3);
            num = fmaf(e0, xg.x, num);
            num = fmaf(e1, xg.y, num);
            num = fmaf(e2, xg.z, num);
            num = fmaf(e3, xg.w, num);
        }

        float o = fmaxf(fmaf(rr, xf, vv * num / den), 0.f);
        __syncthreads();               // all reads of sx done
        sx[r][f] = o;
        xf = o;
        __syncthreads();
    }

    // ---------------- DNN stage 1: h1 = relu(att @ W1 + b1) ----------------
    // 1024 threads = 4 K-chunks (32 i each) x 256 cols. Each thread: 32 loads
    // + 32*8 FMAs, partials to LDS.
    {
        const int j  = tid & 255;      // output column
        const int kq = tid >> 8;       // 0..3 K-chunk
        float acc[RPB];
        #pragma unroll
        for (int q = 0; q < RPB; ++q) acc[q] = 0.f;

        const int i0 = kq * 32;
        #pragma unroll 8
        for (int ii = 0; ii < 32; ++ii) {
            const int i = i0 + ii;
            const float w = W1[i * H1 + j];          // coalesced, L2-hot
            #pragma unroll
            for (int q = 0; q < RPB; ++q)
                acc[q] = fmaf(sx[q][i], w, acc[q]);  // LDS broadcast
        }
        #pragma unroll
        for (int q = 0; q < RPB; ++q)
            part[kq * 2048 + q * 256 + j] = acc[q];
    }
    __syncthreads();
    {
        // reduce 4 partials -> 2048 outputs, 2 per thread
        #pragma unroll
        for (int idx = tid; idx < RPB * H1; idx += 1024) {
            const int q = idx >> 8, j = idx & 255;
            float s = b1[j] + ((part[idx] + part[2048 + idx]) +
                               (part[4096 + idx] + part[6144 + idx]));
            sh1[q][j] = fmaxf(s, 0.f);
        }
    }
    __syncthreads();

    // ---------------- DNN stage 2 + final dot ------------------------------
    // 1024 threads = 8 K-chunks (32 j each) x 128 cols.
    {
        const int k  = tid & 127;
        const int kq = tid >> 7;       // 0..7
        float acc[RPB];
        #pragma unroll
        for (int q = 0; q < RPB; ++q) acc[q] = 0.f;

        const int j0 = kq * 32;
        #pragma unroll 8
        for (int jj = 0; jj < 32; ++jj) {
            const int j = j0 + jj;
            const float w = W2[j * H2 + k];          // coalesced, L2-hot
            #pragma unroll
            for (int q = 0; q < RPB; ++q)
                acc[q] = fmaf(sh1[q][j], w, acc[q]); // LDS broadcast
        }
        #pragma unroll
        for (int q = 0; q < RPB; ++q)
            part[kq * 1024 + q * 128 + k] = acc[q];
    }
    __syncthreads();
    {
        // thread (r2 = tid>>7, k = tid&127): finish h2, multiply Wf, reduce.
        const int r2 = tid >> 7;
        const int k  = tid & 127;
        float s = b2[k];
        #pragma unroll
        for (int q = 0; q < 8; ++q)
            s += part[q * 1024 + r2 * 128 + k];
        float p = fmaxf(s, 0.f) * Wf[k];

        #pragma unroll
        for (int off = 32; off >= 1; off >>= 1)
            p += __shfl_down(p, off, 64);
        if ((tid & 63) == 0)
            red[r2][(tid >> 6) & 1] = p;   // 2 waves per row
    }
    __syncthreads();

    if (tid < RPB)
        out[b0 + tid] = red[tid][0] + red[tid][1];
}

extern "C" void kernel_launch(void* const* d_in, const int* in_sizes, int n_in,
                              void* d_out, int out_size, void* d_ws, size_t ws_size,
                              hipStream_t stream) {
    const float* X  = (const float*)d_in[0];
    const float* wq = (const float*)d_in[1];
    const float* wk = (const float*)d_in[2];
    const float* wv = (const float*)d_in[3];
    const float* wr = (const float*)d_in[4];
    const float* W1 = (const float*)d_in[5];
    const float* b1 = (const float*)d_in[6];
    const float* W2 = (const float*)d_in[7];
    const float* b2 = (const float*)d_in[8];
    const float* Wf = (const float*)d_in[9];
    float* out = (float*)d_out;

    const int B = in_sizes[0] / FDIM;       // 4096
    autoint_fused<<<dim3(B / RPB), dim3(1024), 0, stream>>>(
        X, wq, wk, wv, wr, W1, b1, W2, b2, Wf, out);
}

// Round 14
// 120.057 us; speedup vs baseline: 1.0869x; 1.0696x over previous
//
#include <hip/hip_runtime.h>
#include <hip/hip_bf16.h>

// AutoInt fully-fused kernel for MI355X (gfx950) — R10: occupancy fix.
//
// Reference: X (4096,128) f32 -> 3x InteractingLayer (1x1 SCALAR weights)
//            -> DNN 128->256->128->1.
// Per layer l, row b:  out[f] = relu( wv*(sum_g e_fg*x_g)/(sum_g e_fg) + wr*x_f ),
// e_fg = exp(c*x_f*x_g), c = wq*wk (scalars); log2(e) folded into c -> v_exp_f32.
//
// R9 measured: 1024-thr blocks -> OccupancyPercent 43%, VALUBusy 53%, 64-69 us.
// Latency-bound: 16-wave barrier convoys + ~3.5 waves/SIMD can't hide exp/LDS
// latency. R10: 512-thr blocks, RPB=4, 1024 blocks -> 4 blocks/CU (32 waves),
// 8-wave barriers, double-buffered sx (1 barrier/layer), split accumulators.

#define FDIM 128
#define NLAYER 3
#define RPB 4           // batch rows per block
#define THREADS 512
#define H1 256
#define H2 128

__global__ __launch_bounds__(THREADS, 8) void autoint_fused(
    const float* __restrict__ X,
    const float* __restrict__ wq, const float* __restrict__ wk,
    const float* __restrict__ wv, const float* __restrict__ wr,
    const float* __restrict__ W1, const float* __restrict__ b1,
    const float* __restrict__ W2, const float* __restrict__ b2,
    const float* __restrict__ Wf,
    float* __restrict__ out)
{
    __shared__ float sx[2][RPB][FDIM];   // 4 KB: double-buffered att rows
    __shared__ float sh1[RPB][H1];       // 4 KB: hidden-1 rows
    __shared__ float part[2048];         // 8 KB: K-split partials (both stages)
    __shared__ float red[RPB][2];        // final cross-wave reduction

    const int tid = threadIdx.x;
    const int b0  = blockIdx.x * RPB;

    // ---------------- load 4 rows (coalesced: 1 float/thread) --------------
    const int r = tid >> 7;            // 0..3  (row within block)
    const int f = tid & 127;           // 0..127 (field)
    float xf = X[(b0 + r) * FDIM + f];
    sx[0][r][f] = xf;
    __syncthreads();

    // ---------------- 3 fused interacting layers ---------------------------
    // Double-buffered: read sx[cur], write sx[cur^1]; ONE barrier per layer.
    #pragma unroll
    for (int l = 0; l < NLAYER; ++l) {
        const int cur = l & 1;
        const float c  = wq[l] * wk[l] * 1.4426950408889634f; // fold log2(e)
        const float vv = wv[l];
        const float rr = wr[l];

        const float a = c * xf;
        // split accumulators: halve the fma/add dependency chains
        float den0 = 0.f, den1 = 0.f, num0 = 0.f, num1 = 0.f;

        #pragma unroll 4
        for (int g = 0; g < FDIM; g += 4) {
            // whole wave reads the same 16B of its row -> LDS broadcast
            float4 xg = *reinterpret_cast<const float4*>(&sx[cur][r][g]);
            float e0 = __builtin_amdgcn_exp2f(a * xg.x);
            float e1 = __builtin_amdgcn_exp2f(a * xg.y);
            float e2 = __builtin_amdgcn_exp2f(a * xg.z);
            float e3 = __builtin_amdgcn_exp2f(a * xg.w);
            den0 += e0 + e1;
            den1 += e2 + e3;
            num0 = fmaf(e0, xg.x, num0);
            num1 = fmaf(e1, xg.y, num1);
            num0 = fmaf(e2, xg.z, num0);
            num1 = fmaf(e3, xg.w, num1);
        }

        float o = fmaxf(fmaf(rr, xf, vv * (num0 + num1) / (den0 + den1)), 0.f);
        sx[cur ^ 1][r][f] = o;         // disjoint buffer: safe while others read cur
        xf = o;
        __syncthreads();               // writes visible before next layer reads
    }
    // after 3 layers the live buffer is sx[1] (0->1, 1->0, 0->1)

    // ---------------- DNN stage 1: h1 = relu(att @ W1 + b1) ----------------
    // 512 threads = 2 K-chunks (64 i each) x 256 cols.
    {
        const int j  = tid & 255;      // output column
        const int kq = tid >> 8;       // 0..1 K-chunk
        float acc[RPB];
        #pragma unroll
        for (int q = 0; q < RPB; ++q) acc[q] = 0.f;

        const int i0 = kq * 64;
        #pragma unroll 8
        for (int ii = 0; ii < 64; ++ii) {
            const int i = i0 + ii;
            const float w = W1[i * H1 + j];          // coalesced, L2-hot
            #pragma unroll
            for (int q = 0; q < RPB; ++q)
                acc[q] = fmaf(sx[1][q][i], w, acc[q]);  // LDS broadcast
        }
        #pragma unroll
        for (int q = 0; q < RPB; ++q)
            part[kq * 1024 + q * 256 + j] = acc[q];
    }
    __syncthreads();
    {
        // combine 2 partials -> 1024 outputs, 2 per thread
        #pragma unroll
        for (int idx = tid; idx < RPB * H1; idx += THREADS) {
            const int q = idx >> 8, j = idx & 255;
            float s = b1[j] + part[idx] + part[1024 + idx];
            sh1[q][j] = fmaxf(s, 0.f);
        }
    }
    __syncthreads();

    // ---------------- DNN stage 2 + final dot ------------------------------
    // 512 threads = 4 K-chunks (64 j each) x 128 cols.
    {
        const int k  = tid & 127;
        const int kc = tid >> 7;       // 0..3
        float acc[RPB];
        #pragma unroll
        for (int q = 0; q < RPB; ++q) acc[q] = 0.f;

        const int j0 = kc * 64;
        #pragma unroll 8
        for (int jj = 0; jj < 64; ++jj) {
            const int j = j0 + jj;
            const float w = W2[j * H2 + k];          // coalesced, L2-hot
            #pragma unroll
            for (int q = 0; q < RPB; ++q)
                acc[q] = fmaf(sh1[q][j], w, acc[q]); // LDS broadcast
        }
        #pragma unroll
        for (int q = 0; q < RPB; ++q)
            part[kc * 512 + q * 128 + k] = acc[q];
    }
    __syncthreads();
    {
        // thread (rq = tid>>7, k = tid&127): finish h2, multiply Wf, reduce.
        const int rq = tid >> 7;       // row 0..3
        const int k  = tid & 127;
        float s = b2[k];
        #pragma unroll
        for (int kc = 0; kc < 4; ++kc)
            s += part[kc * 512 + rq * 128 + k];
        float p = fmaxf(s, 0.f) * Wf[k];

        #pragma unroll
        for (int off = 32; off >= 1; off >>= 1)
            p += __shfl_down(p, off, 64);
        if ((tid & 63) == 0)
            red[rq][(tid >> 6) & 1] = p;   // 2 waves per row
    }
    __syncthreads();

    if (tid < RPB)
        out[b0 + tid] = red[tid][0] + red[tid][1];
}

extern "C" void kernel_launch(void* const* d_in, const int* in_sizes, int n_in,
                              void* d_out, int out_size, void* d_ws, size_t ws_size,
                              hipStream_t stream) {
    const float* X  = (const float*)d_in[0];
    const float* wq = (const float*)d_in[1];
    const float* wk = (const float*)d_in[2];
    const float* wv = (const float*)d_in[3];
    const float* wr = (const float*)d_in[4];
    const float* W1 = (const float*)d_in[5];
    const float* b1 = (const float*)d_in[6];
    const float* W2 = (const float*)d_in[7];
    const float* b2 = (const float*)d_in[8];
    const float* Wf = (const float*)d_in[9];
    float* out = (float*)d_out;

    const int B = in_sizes[0] / FDIM;       // 4096
    autoint_fused<<<dim3(B / RPB), dim3(THREADS), 0, stream>>>(
        X, wq, wk, wv, wr, W1, b1, W2, b2, Wf, out);
}

// Round 16
// 118.780 us; speedup vs baseline: 1.0986x; 1.0108x over previous
//
#include <hip/hip_runtime.h>
#include <hip/hip_bf16.h>

// AutoInt fully-fused kernel for MI355X (gfx950) — R14: attn ILP package.
//
// Reference: X (4096,128) f32 -> 3x InteractingLayer (1x1 SCALAR weights)
//            -> DNN 128->256->128->1.
// Per layer l, row b:  out[f] = relu( wv*(sum_g e_fg*x_g)/(sum_g e_fg) + wr*x_f ),
// e_fg = exp(c*x_f*x_g), c = wq*wk (scalars); log2(e) folded into c -> v_exp_f32.
//
// Ledger: R9 1024-thr: 64-69us, occ 43%, VALUBusy 53%. R10 512-thr/RPB=4:
// 58-64us, occ 72-78%, VALUBusy 56-62% -> occupancy fixed but NOT the binding
// stall; ~40% issue-idle persists => intra-wave dependency chains. R14: 8
// elems/iter, 4-way split accumulators, hoisted row ptr. DNN kept verbatim
// (K-split keeps W1/W2 at 1x read per block; de-splitting doubles L2 traffic).

#define FDIM 128
#define NLAYER 3
#define RPB 4           // batch rows per block
#define THREADS 512
#define H1 256
#define H2 128

__global__ __launch_bounds__(THREADS, 8) void autoint_fused(
    const float* __restrict__ X,
    const float* __restrict__ wq, const float* __restrict__ wk,
    const float* __restrict__ wv, const float* __restrict__ wr,
    const float* __restrict__ W1, const float* __restrict__ b1,
    const float* __restrict__ W2, const float* __restrict__ b2,
    const float* __restrict__ Wf,
    float* __restrict__ out)
{
    __shared__ float sx[2][RPB][FDIM];   // 4 KB: double-buffered att rows
    __shared__ float sh1[RPB][H1];       // 4 KB: hidden-1 rows
    __shared__ float part[2048];         // 8 KB: K-split partials (both stages)
    __shared__ float red[RPB][2];        // final cross-wave reduction

    const int tid = threadIdx.x;
    const int b0  = blockIdx.x * RPB;

    // ---------------- load 4 rows (coalesced: 1 float/thread) --------------
    const int r = tid >> 7;            // 0..3  (row within block)
    const int f = tid & 127;           // 0..127 (field)
    float xf = X[(b0 + r) * FDIM + f];
    sx[0][r][f] = xf;
    __syncthreads();

    // ---------------- 3 fused interacting layers ---------------------------
    // Double-buffered: read sx[cur], write sx[cur^1]; ONE barrier per layer.
    // 8 elems/iter, 4-way split accumulators: 8 independent exp chains per
    // window so the mul->exp->fma latency is covered by ILP, not just TLP.
    #pragma unroll
    for (int l = 0; l < NLAYER; ++l) {
        const int cur = l & 1;
        const float c  = wq[l] * wk[l] * 1.4426950408889634f; // fold log2(e)
        const float vv = wv[l];
        const float rr = wr[l];
        const float* __restrict__ row = sx[cur][r];

        const float a = c * xf;
        float den0 = 0.f, den1 = 0.f, den2 = 0.f, den3 = 0.f;
        float num0 = 0.f, num1 = 0.f, num2 = 0.f, num3 = 0.f;

        #pragma unroll 4
        for (int g = 0; g < FDIM; g += 8) {
            // whole wave reads the same 16B -> LDS broadcast, conflict-free
            float4 xa = *reinterpret_cast<const float4*>(row + g);
            float4 xb = *reinterpret_cast<const float4*>(row + g + 4);
            float e0 = __builtin_amdgcn_exp2f(a * xa.x);
            float e1 = __builtin_amdgcn_exp2f(a * xa.y);
            float e2 = __builtin_amdgcn_exp2f(a * xa.z);
            float e3 = __builtin_amdgcn_exp2f(a * xa.w);
            float e4 = __builtin_amdgcn_exp2f(a * xb.x);
            float e5 = __builtin_amdgcn_exp2f(a * xb.y);
            float e6 = __builtin_amdgcn_exp2f(a * xb.z);
            float e7 = __builtin_amdgcn_exp2f(a * xb.w);
            den0 += e0; den1 += e1; den2 += e2; den3 += e3;
            num0 = fmaf(e0, xa.x, num0);
            num1 = fmaf(e1, xa.y, num1);
            num2 = fmaf(e2, xa.z, num2);
            num3 = fmaf(e3, xa.w, num3);
            den0 += e4; den1 += e5; den2 += e6; den3 += e7;
            num0 = fmaf(e4, xb.x, num0);
            num1 = fmaf(e5, xb.y, num1);
            num2 = fmaf(e6, xb.z, num2);
            num3 = fmaf(e7, xb.w, num3);
        }

        const float den = (den0 + den1) + (den2 + den3);
        const float num = (num0 + num1) + (num2 + num3);
        float o = fmaxf(fmaf(rr, xf, vv * num / den), 0.f);
        sx[cur ^ 1][r][f] = o;         // disjoint buffer: safe while others read cur
        xf = o;
        __syncthreads();               // writes visible before next layer reads
    }
    // after 3 layers the live buffer is sx[1] (0->1, 1->0, 0->1)

    // ---------------- DNN stage 1: h1 = relu(att @ W1 + b1) ----------------
    // 512 threads = 2 K-chunks (64 i each) x 256 cols. K-split keeps W1 read
    // exactly once per block (L2-traffic-optimal).
    {
        const int j  = tid & 255;      // output column
        const int kq = tid >> 8;       // 0..1 K-chunk
        float acc[RPB];
        #pragma unroll
        for (int q = 0; q < RPB; ++q) acc[q] = 0.f;

        const int i0 = kq * 64;
        #pragma unroll 8
        for (int ii = 0; ii < 64; ++ii) {
            const int i = i0 + ii;
            const float w = W1[i * H1 + j];          // coalesced, L2-hot
            #pragma unroll
            for (int q = 0; q < RPB; ++q)
                acc[q] = fmaf(sx[1][q][i], w, acc[q]);  // LDS broadcast
        }
        #pragma unroll
        for (int q = 0; q < RPB; ++q)
            part[kq * 1024 + q * 256 + j] = acc[q];
    }
    __syncthreads();
    {
        // combine 2 partials -> 1024 outputs, 2 per thread
        #pragma unroll
        for (int idx = tid; idx < RPB * H1; idx += THREADS) {
            const int q = idx >> 8, j = idx & 255;
            float s = b1[j] + part[idx] + part[1024 + idx];
            sh1[q][j] = fmaxf(s, 0.f);
        }
    }
    __syncthreads();

    // ---------------- DNN stage 2 + final dot ------------------------------
    // 512 threads = 4 K-chunks (64 j each) x 128 cols.
    {
        const int k  = tid & 127;
        const int kc = tid >> 7;       // 0..3
        float acc[RPB];
        #pragma unroll
        for (int q = 0; q < RPB; ++q) acc[q] = 0.f;

        const int j0 = kc * 64;
        #pragma unroll 8
        for (int jj = 0; jj < 64; ++jj) {
            const int j = j0 + jj;
            const float w = W2[j * H2 + k];          // coalesced, L2-hot
            #pragma unroll
            for (int q = 0; q < RPB; ++q)
                acc[q] = fmaf(sh1[q][j], w, acc[q]); // LDS broadcast
        }
        #pragma unroll
        for (int q = 0; q < RPB; ++q)
            part[kc * 512 + q * 128 + k] = acc[q];
    }
    __syncthreads();
    {
        // thread (rq = tid>>7, k = tid&127): finish h2, multiply Wf, reduce.
        const int rq = tid >> 7;       // row 0..3
        const int k  = tid & 127;
        float s = b2[k];
        #pragma unroll
        for (int kc = 0; kc < 4; ++kc)
            s += part[kc * 512 + rq * 128 + k];
        float p = fmaxf(s, 0.f) * Wf[k];

        #pragma unroll
        for (int off = 32; off >= 1; off >>= 1)
            p += __shfl_down(p, off, 64);
        if ((tid & 63) == 0)
            red[rq][(tid >> 6) & 1] = p;   // 2 waves per row
    }
    __syncthreads();

    if (tid < RPB)
        out[b0 + tid] = red[tid][0] + red[tid][1];
}

extern "C" void kernel_launch(void* const* d_in, const int* in_sizes, int n_in,
                              void* d_out, int out_size, void* d_ws, size_t ws_size,
                              hipStream_t stream) {
    const float* X  = (const float*)d_in[0];
    const float* wq = (const float*)d_in[1];
    const float* wk = (const float*)d_in[2];
    const float* wv = (const float*)d_in[3];
    const float* wr = (const float*)d_in[4];
    const float* W1 = (const float*)d_in[5];
    const float* b1 = (const float*)d_in[6];
    const float* W2 = (const float*)d_in[7];
    const float* b2 = (const float*)d_in[8];
    const float* Wf = (const float*)d_in[9];
    float* out = (float*)d_out;

    const int B = in_sizes[0] / FDIM;       // 4096
    autoint_fused<<<dim3(B / RPB), dim3(THREADS), 0, stream>>>(
        X, wq, wk, wv, wr, W1, b1, W2, b2, Wf, out);
}